// Round 2
// baseline (1429.081 us; speedup 1.0000x reference)
//
#include <hip/hip_runtime.h>
#include <cstdint>
#include <cmath>

#define MDIM 4096
#define KDIM 4096
#define NDIM 16384
#define TEST_BOUND -2.053748910631823

typedef unsigned short u16;
typedef __attribute__((ext_vector_type(8))) short short8;
typedef __attribute__((ext_vector_type(4))) float floatx4;

// ---------- fp32 -> bf16 (RNE) conversion ----------
__device__ __forceinline__ u16 f2bf(float f) {
  union { float f; uint32_t u; } c; c.f = f;
  uint32_t r = c.u + 0x7fffu + ((c.u >> 16) & 1u);
  return (u16)(r >> 16);
}

__global__ __launch_bounds__(256) void cvt_kernel(const float4* __restrict__ in,
                                                  ushort4* __restrict__ out, int n4) {
  int stride = gridDim.x * 256;
  for (int i = blockIdx.x * 256 + threadIdx.x; i < n4; i += stride) {
    float4 v = in[i];
    ushort4 o;
    o.x = f2bf(v.x); o.y = f2bf(v.y); o.z = f2bf(v.z); o.w = f2bf(v.w);
    out[i] = o;
  }
}

// ---------- early-stat mask in STRICT f32 (match np f32 einsum semantics) ----------
// numpy einsum 'mk,nk->mn' (optimize=False) sums sequentially over k with
// separate mul/add roundings; xe*xe and we*we are rounded elementwise first.
// We mirror that exactly with never-contracted _rn intrinsics.
__global__ __launch_bounds__(256) void stats_kernel(const float* __restrict__ x,
                                                    const float* __restrict__ w,
                                                    unsigned char* __restrict__ mask) {
  __shared__ float Xs[64][33];  // +1 pad kills bank conflicts on row reads
  __shared__ float Ws[64][33];
  const int bn = blockIdx.x;    // N/64 = 256
  const int bm = blockIdx.y;    // M/64 = 64
  const int t = threadIdx.x;
  for (int e = t; e < 64 * 32; e += 256) {
    int r = e >> 5, c = e & 31;
    Xs[r][c] = x[(size_t)(bm * 64 + r) * KDIM + c];
    Ws[r][c] = w[(size_t)(bn * 64 + r) * KDIM + c];
  }
  __syncthreads();
  const int tn = (t & 15) * 4;
  const int tm = (t >> 4) * 4;
  float y1[4][4] = {}, q[4][4] = {};
  for (int k = 0; k < 32; ++k) {
    float xv[4], wv[4], xx[4], ww[4];
#pragma unroll
    for (int i = 0; i < 4; ++i) { xv[i] = Xs[tm + i][k]; xx[i] = __fmul_rn(xv[i], xv[i]); }
#pragma unroll
    for (int j = 0; j < 4; ++j) { wv[j] = Ws[tn + j][k]; ww[j] = __fmul_rn(wv[j], wv[j]); }
#pragma unroll
    for (int i = 0; i < 4; ++i)
#pragma unroll
      for (int j = 0; j < 4; ++j) {
        y1[i][j] = __fadd_rn(y1[i][j], __fmul_rn(xv[i], wv[j]));
        q[i][j]  = __fadd_rn(q[i][j],  __fmul_rn(xx[i], ww[j]));
      }
  }
#pragma unroll
  for (int i = 0; i < 4; ++i)
#pragma unroll
    for (int j = 0; j < 4; ++j) {
      // inv_n = 0.03125f is a power of two: multiplies are exact scalings,
      // but keep _rn forms to forbid any contraction.
      float mean = __fmul_rn(y1[i][j], 0.03125f);          // STATS_W=1, STATS_B=0
      float var  = __fsub_rn(__fmul_rn(q[i][j], 0.03125f), __fmul_rn(mean, mean));
      float varn = __fmul_rn(var, 0.03125f);
      float den  = __fsqrt_rn(fmaxf(varn, 1e-12f));
      float ts   = __fdiv_rn(mean, den);
      bool passed = ts < (float)TEST_BOUND;
      mask[(size_t)(bm * 64 + tm + i) * NDIM + (bn * 64 + tn + j)] = passed ? 1u : 0u;
    }
}

// ---------- bf16 MFMA GEMM (m97 structure: 128x128 tile, BK=32, global_load_lds) ----------
#define BM 128
#define BN 128
#define BK 32

typedef const __attribute__((address_space(1))) uint32_t* as1_u32p;
typedef __attribute__((address_space(3))) uint32_t* as3_u32p;

__device__ __forceinline__ void async_ld16(const void* g, void* l) {
  // wave-uniform LDS base + lane*16B; per-lane global address
  __builtin_amdgcn_global_load_lds((as1_u32p)g, (as3_u32p)l, 16, 0, 0);
}

__global__ __launch_bounds__(256) void gemm_kernel(const u16* __restrict__ A,
                                                   const u16* __restrict__ B,
                                                   const float* __restrict__ bias,
                                                   const unsigned char* __restrict__ mask,
                                                   float* __restrict__ C) {
  __shared__ __align__(16) u16 As[BM * BK];
  __shared__ __align__(16) u16 Bs[BN * BK];

  const int bid = blockIdx.x;
  const int bm = bid & 31;   // M/128=32 fastest: 32 consecutive blocks reuse one B tile
  const int bn = bid >> 5;   // N/128=128
  const int t = threadIdx.x;
  const int wv = t >> 6;
  const int l = t & 63;
  const int lm = l & 15;
  const int quad = l >> 4;
  const int wm = (wv >> 1) * 64;
  const int wn = (wv & 1) * 64;

  // staging: each issue = 256 threads * 16B = 64 rows of 64B; 2 issues per tile
  const int srow = wv * 16 + (l >> 2);
  const int scol = (l & 3) * 8;
  const size_t a_base = (size_t)(bm * BM) * KDIM;
  const size_t b_base = (size_t)(bn * BN) * KDIM;

  floatx4 acc[4][4];
#pragma unroll
  for (int i = 0; i < 4; ++i)
#pragma unroll
    for (int j = 0; j < 4; ++j) acc[i][j] = (floatx4){0.f, 0.f, 0.f, 0.f};

  for (int k0 = 0; k0 < KDIM; k0 += BK) {
#pragma unroll
    for (int i = 0; i < 2; ++i) {
      async_ld16(A + a_base + (size_t)(i * 64 + srow) * KDIM + k0 + scol,
                 (void*)&As[(i * 64 + wv * 16) * BK]);
      async_ld16(B + b_base + (size_t)(i * 64 + srow) * KDIM + k0 + scol,
                 (void*)&Bs[(i * 64 + wv * 16) * BK]);
    }
    __syncthreads();  // compiler drains vmcnt before s_barrier

    short8 a[4], b[4];
#pragma unroll
    for (int i = 0; i < 4; ++i)
      a[i] = *(const short8*)&As[(wm + i * 16 + lm) * BK + quad * 8];
#pragma unroll
    for (int j = 0; j < 4; ++j)
      b[j] = *(const short8*)&Bs[(wn + j * 16 + lm) * BK + quad * 8];
#pragma unroll
    for (int i = 0; i < 4; ++i)
#pragma unroll
      for (int j = 0; j < 4; ++j)
        acc[i][j] = __builtin_amdgcn_mfma_f32_16x16x32_bf16(a[i], b[j], acc[i][j], 0, 0, 0);
    __syncthreads();
  }

  // epilogue: C/D layout col=lane&15, row=quad*4+reg
  float bv[4];
#pragma unroll
  for (int j = 0; j < 4; ++j) bv[j] = bias[bn * BN + wn + j * 16 + lm];
#pragma unroll
  for (int i = 0; i < 4; ++i)
#pragma unroll
    for (int r = 0; r < 4; ++r) {
      int gm = bm * BM + wm + i * 16 + quad * 4 + r;
      size_t rowoff = (size_t)gm * NDIM + bn * BN + wn;
#pragma unroll
      for (int j = 0; j < 4; ++j) {
        size_t off = rowoff + (size_t)(j * 16 + lm);
        float y = acc[i][j][r] + bv[j];
        C[off] = mask[off] ? 0.0f : y;
      }
    }
}

extern "C" void kernel_launch(void* const* d_in, const int* in_sizes, int n_in,
                              void* d_out, int out_size, void* d_ws, size_t ws_size,
                              hipStream_t stream) {
  const float* x = (const float*)d_in[0];
  const float* w = (const float*)d_in[1];
  const float* bias = (const float*)d_in[2];
  float* out = (float*)d_out;

  // ws layout: xbf (32MB) | wbf (128MB) | mask (64MB) = 224MB
  u16* xbf = (u16*)d_ws;
  u16* wbf = xbf + (size_t)MDIM * KDIM;
  unsigned char* mask = (unsigned char*)(wbf + (size_t)NDIM * KDIM);

  cvt_kernel<<<2048, 256, 0, stream>>>((const float4*)x, (ushort4*)xbf, MDIM * KDIM / 4);
  cvt_kernel<<<8192, 256, 0, stream>>>((const float4*)w, (ushort4*)wbf, NDIM * KDIM / 4);
  stats_kernel<<<dim3(NDIM / 64, MDIM / 64), 256, 0, stream>>>(x, w, mask);
  gemm_kernel<<<(MDIM / BM) * (NDIM / BN), 256, 0, stream>>>(xbf, wbf, bias, mask, out);
}